// Round 1
// baseline (470.959 us; speedup 1.0000x reference)
//
#include <hip/hip_runtime.h>
#include <math.h>

// Problem constants (fixed by the reference: [16,3,1024,1024] fp32 inputs)
#define NP      8       // patches per spatial dim
#define NBINS   256
#define BC      48      // B*C = 16*3
#define HH      1024
#define WW      1024
#define ROWS_PER_BLOCK 32   // 32 | 128 so one h-patch per block
#define THREADS 256
// total rows = BC*HH = 49152 ; grid = 49152/32 = 1536 blocks
#define NBLOCKS 1536
#define PATCH_ELEMS (BC * 128 * 128)         // 786432 elements per patch
#define N_TOTAL ((long long)BC * HH * WW)    // 50331648

// Pass 1: per-patch histogram of hr (exact int counts) + per-patch sum |sr-hr|.
__global__ __launch_bounds__(THREADS)
void entrop_pass1(const float* __restrict__ sr, const float* __restrict__ hr,
                  unsigned int* __restrict__ ghist, float* __restrict__ gsum)
{
    __shared__ unsigned int hist[NP * NBINS];   // [j][bin]
    const int t = threadIdx.x;
    for (int m = t; m < NP * NBINS; m += THREADS) hist[m] = 0;
    __syncthreads();

    const long long r0 = (long long)blockIdx.x * ROWS_PER_BLOCK; // global row
    const int h0 = (int)(r0 & (HH - 1));
    const int i  = h0 >> 7;        // h-patch index (constant over block)
    const int j  = t >> 5;         // w-patch index for this thread (w = 4*t)

    const float4* s4 = (const float4*)sr + r0 * (WW / 4);
    const float4* h4 = (const float4*)hr + r0 * (WW / 4);

    float acc = 0.0f;
    #pragma unroll 4
    for (int r = 0; r < ROWS_PER_BLOCK; ++r) {
        const int idx = r * (WW / 4) + t;
        float4 s = s4[idx];
        float4 h = h4[idx];

        acc += fabsf(s.x - h.x);
        acc += fabsf(s.y - h.y);
        acc += fabsf(s.z - h.z);
        acc += fabsf(s.w - h.w);

        // (v * 255.0f) truncated toward zero, clipped to [0,255] — matches
        // jnp (patches*255.0).astype(int32) then clip.
        int b0 = (int)(h.x * 255.0f); b0 = min(max(b0, 0), 255);
        int b1 = (int)(h.y * 255.0f); b1 = min(max(b1, 0), 255);
        int b2 = (int)(h.z * 255.0f); b2 = min(max(b2, 0), 255);
        int b3 = (int)(h.w * 255.0f); b3 = min(max(b3, 0), 255);
        atomicAdd(&hist[(j << 8) + b0], 1u);
        atomicAdd(&hist[(j << 8) + b1], 1u);
        atomicAdd(&hist[(j << 8) + b2], 1u);
        atomicAdd(&hist[(j << 8) + b3], 1u);
    }

    // Reduce |d| sums within each 32-lane group (all lanes share the same j).
    for (int off = 16; off; off >>= 1) acc += __shfl_down(acc, off, 32);
    if ((t & 31) == 0) atomicAdd(&gsum[i * NP + j], acc);

    __syncthreads();
    // Flush LDS histogram: patch index = i*8 + jj, m = jj*256 + bin.
    for (int m = t; m < NP * NBINS; m += THREADS) {
        unsigned int c = hist[m];
        if (c) atomicAdd(&ghist[(i * NP * NBINS) + m], c);
    }
}

// Pass 2: 64 entropies (fp64), min/max, weighted total -> scalar.
__global__ __launch_bounds__(THREADS)
void entrop_pass2(const unsigned int* __restrict__ ghist,
                  const float* __restrict__ gsum,
                  float* __restrict__ out)
{
    __shared__ double red[THREADS / 64];
    __shared__ double ent[NP * NP];
    const int t = threadIdx.x;
    const double inv_n = 1.0 / (double)PATCH_ELEMS;

    for (int p = 0; p < NP * NP; ++p) {
        unsigned int c = ghist[p * NBINS + t];
        double term = 0.0;
        if (c) {
            double pd = (double)c * inv_n;
            term = pd * log2(pd);
        }
        // wave(64) reduce then cross-wave via LDS
        for (int off = 32; off; off >>= 1) term += __shfl_down(term, off, 64);
        if ((t & 63) == 0) red[t >> 6] = term;
        __syncthreads();
        if (t == 0) ent[p] = -(red[0] + red[1] + red[2] + red[3]);
        __syncthreads();
    }

    if (t == 0) {
        double mn = ent[0], mx = ent[0];
        for (int p = 1; p < NP * NP; ++p) {
            mn = fmin(mn, ent[p]);
            mx = fmax(mx, ent[p]);
        }
        double total = 0.0;
        for (int p = 0; p < NP * NP; ++p) {
            double w = (ent[p] - mn) / mx;     // (w - w.min()) / w.max()
            total += w * (double)gsum[p];
        }
        out[0] = (float)(total / (double)N_TOTAL);
    }
}

extern "C" void kernel_launch(void* const* d_in, const int* in_sizes, int n_in,
                              void* d_out, int out_size, void* d_ws, size_t ws_size,
                              hipStream_t stream)
{
    const float* sr = (const float*)d_in[0];
    const float* hr = (const float*)d_in[1];
    float* out = (float*)d_out;

    unsigned int* ghist = (unsigned int*)d_ws;                     // 64*256 u32 = 64 KiB
    float* gsum = (float*)((char*)d_ws + NP * NP * NBINS * sizeof(unsigned int)); // 64 f32

    const size_t zero_bytes = NP * NP * NBINS * sizeof(unsigned int)
                            + NP * NP * sizeof(float);
    hipMemsetAsync(d_ws, 0, zero_bytes, stream);

    entrop_pass1<<<NBLOCKS, THREADS, 0, stream>>>(sr, hr, ghist, gsum);
    entrop_pass2<<<1, THREADS, 0, stream>>>(ghist, gsum, out);
}

// Round 2
// 405.464 us; speedup vs baseline: 1.1615x; 1.1615x over previous
//
#include <hip/hip_runtime.h>
#include <math.h>

// Problem constants (fixed by the reference: [16,3,1024,1024] fp32 inputs)
#define NP      8
#define NBINS   256
#define BC      48
#define HH      1024
#define WW      1024
#define RPB     16                  // rows per block (16 | 128 -> one h-patch per block)
#define THREADS 256
#define NBLK1   3072                // BC*HH / RPB
#define BLK_PER_I 384               // NBLK1 / NP  (blocks sharing one h-patch index)
#define PATCH_ELEMS (BC * 128 * 128)
#define N_TOTAL ((long long)BC * HH * WW)

// ---- workspace layout (Path A: per-block hist dump, no global atomics) ----
#define GH_BYTES   ((size_t)NBLK1 * 2048 * 2)          // u16 hist per block: 12.58 MB
#define GS_OFF     GH_BYTES
#define GS_BYTES   ((size_t)NBLK1 * NP * 4)            // per-block 8 j-sums: 98 KB
#define ENT_OFF    (GS_OFF + GS_BYTES)                 // 8-byte aligned
#define ENT_BYTES  (64 * 8)
#define GT_OFF     (ENT_OFF + ENT_BYTES)
#define PATHA_BYTES (GT_OFF + 64 * 4)
// ---- Path B (fallback, tiny ws): atomic flush ----
#define B_GHIST_BYTES (64 * NBINS * 4)                 // 64 KB
#define B_GSUM_OFF    B_GHIST_BYTES
#define B_ENT_OFF     (B_GSUM_OFF + 256)               // 8-aligned

__device__ __forceinline__ void load_g(const float4* __restrict__ s4,
                                       const float4* __restrict__ h4,
                                       int g, float4* sb, float4* hb)
{
#pragma unroll
    for (int k = 0; k < 2; ++k) {
        sb[k] = s4[(g * 2 + k) * (WW / 4)];
        hb[k] = h4[(g * 2 + k) * (WW / 4)];
    }
}

__device__ __forceinline__ void proc_g(const float4* sb, const float4* hb,
                                       float& acc, unsigned int* histj)
{
#pragma unroll
    for (int k = 0; k < 2; ++k) {
        float4 s = sb[k], h = hb[k];
        acc += fabsf(s.x - h.x);
        acc += fabsf(s.y - h.y);
        acc += fabsf(s.z - h.z);
        acc += fabsf(s.w - h.w);
        int b0 = min(max((int)(h.x * 255.0f), 0), 255);
        int b1 = min(max((int)(h.y * 255.0f), 0), 255);
        int b2 = min(max((int)(h.z * 255.0f), 0), 255);
        int b3 = min(max((int)(h.w * 255.0f), 0), 255);
        atomicAdd(&histj[b0], 1u);
        atomicAdd(&histj[b1], 1u);
        atomicAdd(&histj[b2], 1u);
        atomicAdd(&histj[b3], 1u);
    }
}

// Pass 1: per-patch histogram + per-patch sum |sr-hr|.
// ATOMIC=false: dump packed-u16 per-block hist (gh32) + plain per-block j-sums (gs)
// ATOMIC=true : global atomicAdd into 64x256 u32 hist + 64 f32 sums
template <bool ATOMIC>
__global__ __launch_bounds__(THREADS, 8)
void entrop_pass1(const float* __restrict__ sr, const float* __restrict__ hr,
                  unsigned int* __restrict__ gh32, float* __restrict__ gs)
{
    __shared__ unsigned int hist[NP * NBINS];
    const int t = threadIdx.x;
#pragma unroll
    for (int m = t; m < NP * NBINS; m += THREADS) hist[m] = 0;
    __syncthreads();

    const int r0 = blockIdx.x * RPB;
    const int i  = (r0 & (HH - 1)) >> 7;    // h-patch (block-uniform)
    const int j  = t >> 5;                  // w-patch for this thread
    unsigned int* histj = &hist[j << 8];

    const float4* s4 = (const float4*)sr + (size_t)r0 * (WW / 4) + t;
    const float4* h4 = (const float4*)hr + (size_t)r0 * (WW / 4) + t;

    float acc = 0.0f;
    float4 sA[2], hA[2], sB[2], hB[2];
    load_g(s4, h4, 0, sA, hA);
#pragma unroll
    for (int g = 0; g < 7; ++g) {
        if (g & 1) { load_g(s4, h4, g + 1, sA, hA); proc_g(sB, hB, acc, histj); }
        else       { load_g(s4, h4, g + 1, sB, hB); proc_g(sA, hA, acc, histj); }
    }
    proc_g(sB, hB, acc, histj);

    // reduce |d| within each 32-lane group (all lanes share j)
    for (int off = 16; off; off >>= 1) acc += __shfl_down(acc, off, 32);
    if ((t & 31) == 0) {
        if (ATOMIC) atomicAdd(&gs[i * NP + j], acc);
        else        gs[blockIdx.x * NP + j] = acc;
    }

    __syncthreads();
    if (ATOMIC) {
        for (int m = t; m < NP * NBINS; m += THREADS) {
            unsigned int c = hist[m];
            if (c) atomicAdd(&gh32[i * NP * NBINS + m], c);
        }
    } else {
        // pack 2 bins per u32 (counts < 2048 per block-bin), coalesced stores
#pragma unroll
        for (int m = t; m < NP * NBINS / 2; m += THREADS)
            gh32[(size_t)blockIdx.x * (NP * NBINS / 2) + m] =
                hist[2 * m] | (hist[2 * m + 1] << 16);
    }
}

// Path A reduce: 64 blocks, one per patch p=(i,j). Sums 384 per-block u16
// hists -> counts -> fp64 entropy; sums 384 per-block j-sums -> gsumT.
__global__ __launch_bounds__(THREADS)
void entrop_reduceA(const unsigned short* __restrict__ gh,
                    const float* __restrict__ gs,
                    double* __restrict__ ent, float* __restrict__ gsumT)
{
    const int p = blockIdx.x, i = p >> 3, jj = p & 7;
    const int t = threadIdx.x;

    unsigned int cnt = 0;
    const unsigned short* col = gh + jj * NBINS + t;
    for (int g = 0; g < BLK_PER_I / 8; ++g) {
#pragma unroll
        for (int d = 0; d < 8; ++d)
            cnt += col[(size_t)(64 * g + 8 * i + d) * 2048];
    }
    double term = 0.0;
    if (cnt) {
        double pd = (double)cnt * (1.0 / (double)PATCH_ELEMS);
        term = pd * log2(pd);
    }
    float sg = 0.0f;
    for (int idx = t; idx < BLK_PER_I; idx += THREADS) {
        int g = idx >> 3, d = idx & 7;
        sg += gs[(size_t)(64 * g + 8 * i + d) * NP + jj];
    }

    for (int off = 32; off; off >>= 1) {
        term += __shfl_down(term, off, 64);
        sg   += __shfl_down(sg, off, 64);
    }
    __shared__ double rd[4];
    __shared__ float  rf[4];
    if ((t & 63) == 0) { rd[t >> 6] = term; rf[t >> 6] = sg; }
    __syncthreads();
    if (t == 0) {
        ent[p]   = -(rd[0] + rd[1] + rd[2] + rd[3]);
        gsumT[p] = rf[0] + rf[1] + rf[2] + rf[3];
    }
}

// Path B reduce: entropy from the atomically-accumulated u32 hist.
__global__ __launch_bounds__(THREADS)
void entrop_reduceB(const unsigned int* __restrict__ ghist, double* __restrict__ ent)
{
    const int p = blockIdx.x, t = threadIdx.x;
    unsigned int c = ghist[p * NBINS + t];
    double term = 0.0;
    if (c) {
        double pd = (double)c * (1.0 / (double)PATCH_ELEMS);
        term = pd * log2(pd);
    }
    for (int off = 32; off; off >>= 1) term += __shfl_down(term, off, 64);
    __shared__ double rd[4];
    if ((t & 63) == 0) rd[t >> 6] = term;
    __syncthreads();
    if (t == 0) ent[p] = -(rd[0] + rd[1] + rd[2] + rd[3]);
}

// Final: 1 wave. min/max over 64 entropies, weighted sum, scalar out.
__global__ void entrop_final(const double* __restrict__ ent,
                             const float* __restrict__ gsumT,
                             float* __restrict__ out)
{
    const int t = threadIdx.x;   // 64 threads
    double e = ent[t];
    double mn = e, mx = e;
#pragma unroll
    for (int off = 32; off; off >>= 1) {
        mn = fmin(mn, __shfl_xor(mn, off, 64));
        mx = fmax(mx, __shfl_xor(mx, off, 64));
    }
    double contrib = (e - mn) / mx * (double)gsumT[t];
#pragma unroll
    for (int off = 32; off; off >>= 1) contrib += __shfl_xor(contrib, off, 64);
    if (t == 0) out[0] = (float)(contrib / (double)N_TOTAL);
}

extern "C" void kernel_launch(void* const* d_in, const int* in_sizes, int n_in,
                              void* d_out, int out_size, void* d_ws, size_t ws_size,
                              hipStream_t stream)
{
    const float* sr = (const float*)d_in[0];
    const float* hr = (const float*)d_in[1];
    float* out = (float*)d_out;
    char* ws = (char*)d_ws;

    if (ws_size >= PATHA_BYTES) {
        unsigned int*   gh32  = (unsigned int*)ws;                 // u16 hists, u32-packed
        float*          gs    = (float*)(ws + GS_OFF);
        double*         ent   = (double*)(ws + ENT_OFF);
        float*          gsumT = (float*)(ws + GT_OFF);
        // everything fully overwritten before read -> no memset needed
        entrop_pass1<false><<<NBLK1, THREADS, 0, stream>>>(sr, hr, gh32, gs);
        entrop_reduceA<<<64, THREADS, 0, stream>>>((const unsigned short*)gh32, gs, ent, gsumT);
        entrop_final<<<1, 64, 0, stream>>>(ent, gsumT, out);
    } else {
        unsigned int* ghist = (unsigned int*)ws;
        float*        gsum  = (float*)(ws + B_GSUM_OFF);
        double*       ent   = (double*)(ws + B_ENT_OFF);
        hipMemsetAsync(ws, 0, B_GSUM_OFF + 256, stream);
        entrop_pass1<true><<<NBLK1, THREADS, 0, stream>>>(sr, hr, ghist, gsum);
        entrop_reduceB<<<64, THREADS, 0, stream>>>(ghist, ent);
        entrop_final<<<1, 64, 0, stream>>>(ent, gsum, out);
    }
}